// Round 5
// baseline (3820.058 us; speedup 1.0000x reference)
//
#include <hip/hip_runtime.h>
#include <cstddef>

#define INPUT_D 100
#define HID 64
#define BATCH 1024
#define SEQT 512
#define TC 8
#define NCHUNK (SEQT / TC)   // 64
#define BB 2
#define NB (BATCH / BB)      // 512 blocks of 512 threads

__device__ __forceinline__ float sigm(float x) {
    return __builtin_amdgcn_rcpf(1.0f + __expf(-x));
}
__device__ __forceinline__ float tanh_f(float x) {
    float e = __expf(2.0f * x);
    return 1.0f - 2.0f * __builtin_amdgcn_rcpf(e + 1.0f);
}
// broadcast lane `l` of per-lane value v (l must be wave-uniform -> SGPR)
__device__ __forceinline__ float bcast(int v, int l) {
    return __int_as_float(__builtin_amdgcn_readlane(v, l));
}

__global__ __launch_bounds__(512, 2) void lstm2_fused(
    const float* __restrict__ x,
    const float* __restrict__ Wih0, const float* __restrict__ Whh0,
    const float* __restrict__ bih0, const float* __restrict__ bhh0,
    const float* __restrict__ Wih1, const float* __restrict__ Whh1,
    const float* __restrict__ bih1, const float* __restrict__ bhh1,
    const float* __restrict__ fcw, const float* __restrict__ fcb,
    float* __restrict__ y)
{
    __shared__ __align__(16) float xs[BB][TC * INPUT_D];  // 6.4 KB
    __shared__ float xg[TC][BB][256];                     // 16 KB (bias0 + Wih0·x)
    __shared__ __align__(8) float h0s[HID][BB];
    __shared__ __align__(8) float h1s[HID][BB];
    __shared__ __align__(8) float pb_L0[2][256][BB];      // whh0·h0 halves (for NEXT step L0)
    __shared__ __align__(8) float pb_L1[2][256][BB];      // wih1·h0 halves (cur step L1)
    __shared__ __align__(8) float pb_W1[2][256][BB];      // bias1 + whh1·h1 halves (next step L1)
    __shared__ float ybuf[TC][BB];

    const int t    = threadIdx.x;
    const int lane = t & 63;
    const int wv   = t >> 6;                 // wave id 0..7
    const int kh   = wv & 1;                 // k-half (wave-uniform)
    const int q    = wv >> 1;                // row group 0..3
    const int r    = q * 64 + lane;          // owned gate-row 0..255
    const int khBase = __builtin_amdgcn_readfirstlane(kh * 32);  // SGPR for readlane
    const int bbase = blockIdx.x * BB;

    // ---- per-thread weight halves: 96 floats ----
    float w0h[32], w1i[32], w1h[32];
    {
        const size_t o = (size_t)r * HID + kh * 32;
        #pragma unroll
        for (int kk = 0; kk < 32; kk += 4) {
            *(float4*)(w0h + kk) = *(const float4*)(Whh0 + o + kk);
            *(float4*)(w1i + kk) = *(const float4*)(Wih1 + o + kk);
            *(float4*)(w1h + kk) = *(const float4*)(Whh1 + o + kk);
        }
    }
    const float bias1B = (kh == 0) ? (bih1[r] + bhh1[r]) : 0.0f;

    // phase-A identity: row pair (p, p+128), col group cg (4 cols of 16)
    const int p  = t & 127;
    const int cg = t >> 7;
    const float b0a = bih0[p] + bhh0[p];
    const float b0b = bih0[p + 128] + bhh0[p + 128];

    // update-thread state (valid for t<128): b = t>>6, u = t&63
    const int uu = t & 63;
    const int ub = (t >> 6) & 1;
    float c0 = 0.f, c1 = 0.f;
    const float fw = fcw[uu];
    const float fb = fcb[0];

    // ---- init carried partial buffers (step -1 state) ----
    *(float2*)&pb_L0[kh][r][0] = make_float2(0.f, 0.f);
    *(float2*)&pb_W1[kh][r][0] = make_float2(bias1B, bias1B);

    for (int ch = 0; ch < NCHUNK; ++ch) {
        // ---------- stage x chunk: 1600 floats = 400 float4 ----------
        if (t < 400) {
            const int e = t * 4;
            const int b = (e >= TC * INPUT_D) ? 1 : 0;
            const int off = e - b * (TC * INPUT_D);
            const float4 v = *(const float4*)(
                x + ((size_t)(bbase + b) * SEQT + (size_t)ch * TC) * INPUT_D + off);
            *(float4*)&xs[b][off] = v;
        }
        __syncthreads();

        // ---------- phase A: xg = bias0 + Wih0·x  (rows p,p+128 × 4 cols) ----------
        {
            float acc0[4], acc1[4];
            #pragma unroll
            for (int j = 0; j < 4; ++j) { acc0[j] = b0a; acc1[j] = b0b; }
            const float* wa = Wih0 + (size_t)p * INPUT_D;
            const float* wb = Wih0 + (size_t)(p + 128) * INPUT_D;
            #pragma unroll 5
            for (int kq = 0; kq < INPUT_D / 4; ++kq) {
                const float4 va = *(const float4*)(wa + kq * 4);
                const float4 vb = *(const float4*)(wb + kq * 4);
                #pragma unroll
                for (int j = 0; j < 4; ++j) {
                    const int c  = cg * 4 + j;       // col = tc*2 + b
                    const int tc = c >> 1, b = c & 1;
                    const float4 xv = *(const float4*)(&xs[b][tc * INPUT_D + kq * 4]);
                    acc0[j] = fmaf(va.x, xv.x, acc0[j]);
                    acc0[j] = fmaf(va.y, xv.y, acc0[j]);
                    acc0[j] = fmaf(va.z, xv.z, acc0[j]);
                    acc0[j] = fmaf(va.w, xv.w, acc0[j]);
                    acc1[j] = fmaf(vb.x, xv.x, acc1[j]);
                    acc1[j] = fmaf(vb.y, xv.y, acc1[j]);
                    acc1[j] = fmaf(vb.z, xv.z, acc1[j]);
                    acc1[j] = fmaf(vb.w, xv.w, acc1[j]);
                }
            }
            #pragma unroll
            for (int j = 0; j < 4; ++j) {
                const int c = cg * 4 + j;
                const int tc = c >> 1, b = c & 1;
                xg[tc][b][p]       = acc0[j];
                xg[tc][b][p + 128] = acc1[j];
            }
        }
        __syncthreads();

        // ---------- phase B: TC recurrent steps ----------
        for (int tc = 0; tc < TC; ++tc) {
            // phase 2: layer-0 update (t<128): gates = pb_L0 halves + xg
            if (t < 128) {
                float sv[4];
                #pragma unroll
                for (int g = 0; g < 4; ++g) {
                    const int rg = g * 64 + uu;
                    sv[g] = pb_L0[0][rg][ub] + pb_L0[1][rg][ub] + xg[tc][ub][rg];
                }
                const float iv = sigm(sv[0]), fv = sigm(sv[1]);
                const float gv = tanh_f(sv[2]), ov = sigm(sv[3]);
                c0 = fmaf(fv, c0, iv * gv);
                h0s[uu][ub] = ov * tanh_f(c0);
            }
            __syncthreads();  // bar-A: h0(t) visible

            // phase 3+4: consume h0(t): whh0·h0 (next L0) and wih1·h0 (cur L1)
            {
                const float2 hv = *(const float2*)&h0s[lane][0];
                const int hb0 = __float_as_int(hv.x), hb1 = __float_as_int(hv.y);
                float aL0b0 = 0.f, aL0b1 = 0.f, aL1b0 = 0.f, aL1b1 = 0.f;
                #pragma unroll
                for (int kk = 0; kk < 32; ++kk) {
                    const float x0 = bcast(hb0, khBase + kk);
                    const float x1 = bcast(hb1, khBase + kk);
                    aL0b0 = fmaf(w0h[kk], x0, aL0b0);
                    aL0b1 = fmaf(w0h[kk], x1, aL0b1);
                    aL1b0 = fmaf(w1i[kk], x0, aL1b0);
                    aL1b1 = fmaf(w1i[kk], x1, aL1b1);
                }
                *(float2*)&pb_L0[kh][r][0] = make_float2(aL0b0, aL0b1);
                *(float2*)&pb_L1[kh][r][0] = make_float2(aL1b0, aL1b1);
            }
            __syncthreads();  // bar-B: partials visible

            // phase 5: layer-1 update + FC (t<128)
            if (t < 128) {
                float sv[4];
                #pragma unroll
                for (int g = 0; g < 4; ++g) {
                    const int rg = g * 64 + uu;
                    sv[g] = pb_L1[0][rg][ub] + pb_L1[1][rg][ub]
                          + pb_W1[0][rg][ub] + pb_W1[1][rg][ub];
                }
                const float iv = sigm(sv[0]), fv = sigm(sv[1]);
                const float gv = tanh_f(sv[2]), ov = sigm(sv[3]);
                c1 = fmaf(fv, c1, iv * gv);
                const float h = ov * tanh_f(c1);
                h1s[uu][ub] = h;
                float pr = fw * h;
                #pragma unroll
                for (int off = 32; off >= 1; off >>= 1) pr += __shfl_xor(pr, off, 64);
                if (uu == 0) ybuf[tc][ub] = pr + fb;
            }
            __syncthreads();  // bar-C: h1(t) visible

            // phase 6+7: consume h1(t): bias1 + whh1·h1 (next L1 partial)
            {
                const float2 hv = *(const float2*)&h1s[lane][0];
                const int hb0 = __float_as_int(hv.x), hb1 = __float_as_int(hv.y);
                float aWb0 = bias1B, aWb1 = bias1B;
                #pragma unroll
                for (int kk = 0; kk < 32; ++kk) {
                    const float x0 = bcast(hb0, khBase + kk);
                    const float x1 = bcast(hb1, khBase + kk);
                    aWb0 = fmaf(w1h[kk], x0, aWb0);
                    aWb1 = fmaf(w1h[kk], x1, aWb1);
                }
                *(float2*)&pb_W1[kh][r][0] = make_float2(aWb0, aWb1);
            }
            __syncthreads();  // bar-D: end of step
        }

        // ---------- store y chunk ----------
        if (t < TC * BB) {
            const int b = t / TC, tt = t % TC;
            y[(size_t)(bbase + b) * SEQT + (size_t)ch * TC + tt] = ybuf[tt][b];
        }
        // ordered: next writes to ybuf happen after ≥3 barriers
    }
}

extern "C" void kernel_launch(void* const* d_in, const int* in_sizes, int n_in,
                              void* d_out, int out_size, void* d_ws, size_t ws_size,
                              hipStream_t stream) {
    const float* x    = (const float*)d_in[0];
    const float* Wih0 = (const float*)d_in[1];
    const float* Whh0 = (const float*)d_in[2];
    const float* bih0 = (const float*)d_in[3];
    const float* bhh0 = (const float*)d_in[4];
    const float* Wih1 = (const float*)d_in[5];
    const float* Whh1 = (const float*)d_in[6];
    const float* bih1 = (const float*)d_in[7];
    const float* bhh1 = (const float*)d_in[8];
    const float* fcw  = (const float*)d_in[9];
    const float* fcb  = (const float*)d_in[10];
    float* y = (float*)d_out;

    lstm2_fused<<<NB, 512, 0, stream>>>(x, Wih0, Whh0, bih0, bhh0,
                                        Wih1, Whh1, bih1, bhh1, fcw, fcb, y);
}

// Round 6
// 3708.974 us; speedup vs baseline: 1.0300x; 1.0300x over previous
//
#include <hip/hip_runtime.h>
#include <cstddef>

#define INPUT_D 100
#define HID 64
#define BATCH 1024
#define SEQT 512
#define TC 8
#define NCHUNK (SEQT / TC)   // 64
#define BB 2
#define NB (BATCH / BB)      // 512 blocks of 512 threads

__device__ __forceinline__ float sigm(float x) {
    return __builtin_amdgcn_rcpf(1.0f + __expf(-x));
}
__device__ __forceinline__ float tanh_f(float x) {
    float e = __expf(2.0f * x);
    return 1.0f - 2.0f * __builtin_amdgcn_rcpf(e + 1.0f);
}
// broadcast lane `l` of per-lane value v (l must be wave-uniform -> SGPR)
__device__ __forceinline__ float bcast(int v, int l) {
    return __int_as_float(__builtin_amdgcn_readlane(v, l));
}

__global__ __launch_bounds__(512, 1) void lstm2_fused(
    const float* __restrict__ x,
    const float* __restrict__ Wih0, const float* __restrict__ Whh0,
    const float* __restrict__ bih0, const float* __restrict__ bhh0,
    const float* __restrict__ Wih1, const float* __restrict__ Whh1,
    const float* __restrict__ bih1, const float* __restrict__ bhh1,
    const float* __restrict__ fcw, const float* __restrict__ fcb,
    float* __restrict__ y)
{
    __shared__ __align__(16) float xs[BB][TC * INPUT_D];  // 6.4 KB
    __shared__ float xg[TC][BB][256];                     // 16 KB (bias0 + Wih0·x)
    // bank-friendly layouts: fastest dim indexed by lane -> 2-way (free)
    __shared__ float h0s[BB][HID];
    __shared__ float h1s[BB][HID];
    __shared__ float pb_L0[2][BB][256];   // whh0·h0 halves (for NEXT step L0)
    __shared__ float pb_L1[2][BB][256];   // wih1·h0 halves (cur step L1)
    __shared__ float pb_W1[2][BB][256];   // bias1 + whh1·h1 halves (next step L1)
    __shared__ float ybuf[TC][BB];

    const int t    = threadIdx.x;
    const int lane = t & 63;
    const int wv   = t >> 6;                 // wave id 0..7
    const int kh   = wv & 1;                 // k-half (wave-uniform)
    const int q    = wv >> 1;                // row group 0..3
    const int r    = q * 64 + lane;          // owned gate-row 0..255
    const int khBase = __builtin_amdgcn_readfirstlane(kh * 32);  // SGPR for readlane
    const int bbase = blockIdx.x * BB;

    // ---- per-thread weight halves: 96 floats (register-resident) ----
    float w0h[32], w1i[32], w1h[32];
    {
        const size_t o = (size_t)r * HID + kh * 32;
        #pragma unroll
        for (int kk = 0; kk < 32; kk += 4) {
            *(float4*)(w0h + kk) = *(const float4*)(Whh0 + o + kk);
            *(float4*)(w1i + kk) = *(const float4*)(Wih1 + o + kk);
            *(float4*)(w1h + kk) = *(const float4*)(Whh1 + o + kk);
        }
    }
    const float bias1B = (kh == 0) ? (bih1[r] + bhh1[r]) : 0.0f;

    // phase-A identity: row pair (p, p+128), col group cg (4 cols of 16)
    const int p  = t & 127;
    const int cg = t >> 7;
    const float b0a = bih0[p] + bhh0[p];
    const float b0b = bih0[p + 128] + bhh0[p + 128];

    // update-thread state (valid for t<128): b = t>>6, u = t&63
    const int uu = t & 63;
    const int ub = (t >> 6) & 1;
    float c0 = 0.f, c1 = 0.f;
    const float fw = fcw[uu];
    const float fb = fcb[0];

    // ---- init carried partial buffers (step -1 state) ----
    pb_L0[kh][0][r] = 0.f;
    pb_L0[kh][1][r] = 0.f;
    pb_W1[kh][0][r] = bias1B;
    pb_W1[kh][1][r] = bias1B;

    for (int ch = 0; ch < NCHUNK; ++ch) {
        // ---------- stage x chunk: 1600 floats = 400 float4 ----------
        if (t < 400) {
            const int e = t * 4;
            const int b = (e >= TC * INPUT_D) ? 1 : 0;
            const int off = e - b * (TC * INPUT_D);
            const float4 v = *(const float4*)(
                x + ((size_t)(bbase + b) * SEQT + (size_t)ch * TC) * INPUT_D + off);
            *(float4*)&xs[b][off] = v;
        }
        __syncthreads();

        // ---------- phase A: xg = bias0 + Wih0·x  (rows p,p+128 × 4 cols) ----------
        {
            float acc0[4], acc1[4];
            #pragma unroll
            for (int j = 0; j < 4; ++j) { acc0[j] = b0a; acc1[j] = b0b; }
            const float* wa = Wih0 + (size_t)p * INPUT_D;
            const float* wb = Wih0 + (size_t)(p + 128) * INPUT_D;
            #pragma unroll 5
            for (int kq = 0; kq < INPUT_D / 4; ++kq) {
                const float4 va = *(const float4*)(wa + kq * 4);
                const float4 vb = *(const float4*)(wb + kq * 4);
                #pragma unroll
                for (int j = 0; j < 4; ++j) {
                    const int c  = cg * 4 + j;       // col = tc*2 + b
                    const int tc = c >> 1, b = c & 1;
                    const float4 xv = *(const float4*)(&xs[b][tc * INPUT_D + kq * 4]);
                    acc0[j] = fmaf(va.x, xv.x, acc0[j]);
                    acc0[j] = fmaf(va.y, xv.y, acc0[j]);
                    acc0[j] = fmaf(va.z, xv.z, acc0[j]);
                    acc0[j] = fmaf(va.w, xv.w, acc0[j]);
                    acc1[j] = fmaf(vb.x, xv.x, acc1[j]);
                    acc1[j] = fmaf(vb.y, xv.y, acc1[j]);
                    acc1[j] = fmaf(vb.z, xv.z, acc1[j]);
                    acc1[j] = fmaf(vb.w, xv.w, acc1[j]);
                }
            }
            #pragma unroll
            for (int j = 0; j < 4; ++j) {
                const int c = cg * 4 + j;
                const int tc = c >> 1, b = c & 1;
                xg[tc][b][p]       = acc0[j];
                xg[tc][b][p + 128] = acc1[j];
            }
        }
        __syncthreads();

        // ---------- phase B: TC recurrent steps ----------
        for (int tc = 0; tc < TC; ++tc) {
            // phase 2: layer-0 update (t<128): gates = pb_L0 halves + xg
            if (t < 128) {
                float sv[4];
                #pragma unroll
                for (int g = 0; g < 4; ++g) {
                    const int rg = g * 64 + uu;
                    sv[g] = pb_L0[0][ub][rg] + pb_L0[1][ub][rg] + xg[tc][ub][rg];
                }
                const float iv = sigm(sv[0]), fv = sigm(sv[1]);
                const float gv = tanh_f(sv[2]), ov = sigm(sv[3]);
                c0 = fmaf(fv, c0, iv * gv);
                h0s[ub][uu] = ov * tanh_f(c0);
            }
            __syncthreads();  // bar-A: h0(t) visible

            // phase 3+4: consume h0(t): whh0·h0 (next L0) and wih1·h0 (cur L1)
            {
                const int hb0 = __float_as_int(h0s[0][lane]);
                const int hb1 = __float_as_int(h0s[1][lane]);
                float aL0b0 = 0.f, aL0b1 = 0.f, aL1b0 = 0.f, aL1b1 = 0.f;
                #pragma unroll
                for (int kk = 0; kk < 32; ++kk) {
                    const float x0 = bcast(hb0, khBase + kk);
                    const float x1 = bcast(hb1, khBase + kk);
                    aL0b0 = fmaf(w0h[kk], x0, aL0b0);
                    aL0b1 = fmaf(w0h[kk], x1, aL0b1);
                    aL1b0 = fmaf(w1i[kk], x0, aL1b0);
                    aL1b1 = fmaf(w1i[kk], x1, aL1b1);
                }
                pb_L0[kh][0][r] = aL0b0;
                pb_L0[kh][1][r] = aL0b1;
                pb_L1[kh][0][r] = aL1b0;
                pb_L1[kh][1][r] = aL1b1;
            }
            __syncthreads();  // bar-B: partials visible

            // phase 5: layer-1 update + FC (t<128)
            if (t < 128) {
                float sv[4];
                #pragma unroll
                for (int g = 0; g < 4; ++g) {
                    const int rg = g * 64 + uu;
                    sv[g] = pb_L1[0][ub][rg] + pb_L1[1][ub][rg]
                          + pb_W1[0][ub][rg] + pb_W1[1][ub][rg];
                }
                const float iv = sigm(sv[0]), fv = sigm(sv[1]);
                const float gv = tanh_f(sv[2]), ov = sigm(sv[3]);
                c1 = fmaf(fv, c1, iv * gv);
                const float h = ov * tanh_f(c1);
                h1s[ub][uu] = h;
                float pr = fw * h;
                #pragma unroll
                for (int off = 32; off >= 1; off >>= 1) pr += __shfl_xor(pr, off, 64);
                if (uu == 0) ybuf[tc][ub] = pr + fb;
            }
            __syncthreads();  // bar-C: h1(t) visible

            // phase 6+7: consume h1(t): bias1 + whh1·h1 (next L1 partial)
            {
                const int hb0 = __float_as_int(h1s[0][lane]);
                const int hb1 = __float_as_int(h1s[1][lane]);
                float aWb0 = bias1B, aWb1 = bias1B;
                #pragma unroll
                for (int kk = 0; kk < 32; ++kk) {
                    const float x0 = bcast(hb0, khBase + kk);
                    const float x1 = bcast(hb1, khBase + kk);
                    aWb0 = fmaf(w1h[kk], x0, aWb0);
                    aWb1 = fmaf(w1h[kk], x1, aWb1);
                }
                pb_W1[kh][0][r] = aWb0;
                pb_W1[kh][1][r] = aWb1;
            }
            __syncthreads();  // bar-D: end of step
        }

        // ---------- store y chunk ----------
        if (t < TC * BB) {
            const int b = t / TC, tt = t % TC;
            y[(size_t)(bbase + b) * SEQT + (size_t)ch * TC + tt] = ybuf[tt][b];
        }
        // ordered: next writes to ybuf happen after ≥3 barriers
    }
}

extern "C" void kernel_launch(void* const* d_in, const int* in_sizes, int n_in,
                              void* d_out, int out_size, void* d_ws, size_t ws_size,
                              hipStream_t stream) {
    const float* x    = (const float*)d_in[0];
    const float* Wih0 = (const float*)d_in[1];
    const float* Whh0 = (const float*)d_in[2];
    const float* bih0 = (const float*)d_in[3];
    const float* bhh0 = (const float*)d_in[4];
    const float* Wih1 = (const float*)d_in[5];
    const float* Whh1 = (const float*)d_in[6];
    const float* bih1 = (const float*)d_in[7];
    const float* bhh1 = (const float*)d_in[8];
    const float* fcw  = (const float*)d_in[9];
    const float* fcb  = (const float*)d_in[10];
    float* y = (float*)d_out;

    lstm2_fused<<<NB, 512, 0, stream>>>(x, Wih0, Whh0, bih0, bhh0,
                                        Wih1, Whh1, bih1, bhh1, fcw, fcb, y);
}

// Round 7
// 2381.087 us; speedup vs baseline: 1.6043x; 1.5577x over previous
//
#include <hip/hip_runtime.h>
#include <cstddef>

#define INPUT_D 100
#define HID 64
#define BATCH 1024
#define SEQT 512
#define TC 8
#define NCHUNK (SEQT / TC)   // 64
#define BB 2
#define NB (BATCH / BB)      // 512 blocks of 256 threads

__device__ __forceinline__ float sigm(float x) {
    return __builtin_amdgcn_rcpf(1.0f + __expf(-x));
}
__device__ __forceinline__ float tanh_f(float x) {
    float e = __expf(2.0f * x);
    return 1.0f - 2.0f * __builtin_amdgcn_rcpf(e + 1.0f);
}

__global__ __launch_bounds__(256, 2) void lstm2_fused(
    const float* __restrict__ x,
    const float* __restrict__ Wih0, const float* __restrict__ Whh0,
    const float* __restrict__ bih0, const float* __restrict__ bhh0,
    const float* __restrict__ Wih1, const float* __restrict__ Whh1,
    const float* __restrict__ bih1, const float* __restrict__ bhh1,
    const float* __restrict__ fcw, const float* __restrict__ fcb,
    float* __restrict__ y)
{
    __shared__ __align__(16) float xs[BB][TC * INPUT_D];   // 6.4 KB
    __shared__ __align__(16) float xg[TC][BB][256];        // 16 KB
    __shared__ __align__(16) float h0s[BB][HID];           // h0(t)
    __shared__ __align__(16) float h1s[BB][HID];           // h1(t-1)
    __shared__ float pL0[2][BB][256];  // [kh][b][r]: whh0·h0 halves
    __shared__ float pL1[2][BB][256];  // wih1·h0 halves
    __shared__ float pW1[2][BB][256];  // whh1·h1 halves

    const int t   = threadIdx.x;
    const int ut  = t & 63;            // lane / unit
    const int kh  = t >> 7;            // k-half (waves 0-1: 0, waves 2-3: 1)
    const int rp  = t & 127;           // owns rows rp and rp+128
    const int ub  = (t >> 6) & 1;      // batch for update phase
    const int bbase = blockIdx.x * BB;

    // ---- recurrent weights: 2 rows x 32 k x 3 matrices = 192 regs ----
    float w0a[32], w0b[32], wia[32], wib[32], wha[32], whb[32];
    {
        const size_t oa = (size_t)rp * HID + kh * 32;
        const size_t ob = (size_t)(rp + 128) * HID + kh * 32;
        #pragma unroll
        for (int kk = 0; kk < 32; kk += 4) {
            *(float4*)(w0a + kk) = *(const float4*)(Whh0 + oa + kk);
            *(float4*)(w0b + kk) = *(const float4*)(Whh0 + ob + kk);
            *(float4*)(wia + kk) = *(const float4*)(Wih1 + oa + kk);
            *(float4*)(wib + kk) = *(const float4*)(Wih1 + ob + kk);
            *(float4*)(wha + kk) = *(const float4*)(Whh1 + oa + kk);
            *(float4*)(whb + kk) = *(const float4*)(Whh1 + ob + kk);
        }
    }

    // phase-A identity: rows ra..ra+3, cols (t>>6)*4..+3 (wave-uniform cols)
    const int ra = ut * 4;
    float b0r[4];
    #pragma unroll
    for (int i2 = 0; i2 < 4; ++i2) b0r[i2] = bih0[ra + i2] + bhh0[ra + i2];

    // update-phase constants
    float b1r[4];
    #pragma unroll
    for (int g = 0; g < 4; ++g) b1r[g] = bih1[g * 64 + ut] + bhh1[g * 64 + ut];
    const float fw = fcw[ut];
    const float fb = fcb[0];
    float c0 = 0.f, c1 = 0.f;

    // ---- init: h1(-1) = 0, pL0 = 0 ----
    if (t < 128) h1s[ub][ut] = 0.f;
    pL0[kh][0][rp] = 0.f;
    pL0[kh][1][rp] = 0.f;
    pL0[kh][0][rp + 128] = 0.f;
    pL0[kh][1][rp + 128] = 0.f;

    for (int ch = 0; ch < NCHUNK; ++ch) {
        // ---------- stage x chunk: 1600 floats = 400 float4 ----------
        {
            const size_t xb = ((size_t)bbase * SEQT + (size_t)ch * TC) * INPUT_D;
            {
                const int e = t * 4;
                const int b = (e >= TC * INPUT_D) ? 1 : 0;
                const int off = e - b * (TC * INPUT_D);
                *(float4*)&xs[b][off] =
                    *(const float4*)(x + xb + (size_t)b * SEQT * INPUT_D + off);
            }
            if (t < 144) {
                const int e = (t + 256) * 4;
                const int off = e - (TC * INPUT_D);   // always batch 1
                *(float4*)&xs[1][off] =
                    *(const float4*)(x + xb + (size_t)SEQT * INPUT_D + off);
            }
        }
        __syncthreads();

        // ---------- phase A: xg = bias0 + Wih0·x (4 rows x 4 cols) ----------
        {
            const int cg = t >> 6;   // wave-uniform col group
            float acc[4][4];
            #pragma unroll
            for (int i2 = 0; i2 < 4; ++i2)
                #pragma unroll
                for (int j = 0; j < 4; ++j) acc[i2][j] = b0r[i2];
            #pragma unroll 5
            for (int kq = 0; kq < INPUT_D / 4; ++kq) {
                float4 xv[4];
                #pragma unroll
                for (int j = 0; j < 4; ++j) {
                    const int c = cg * 4 + j, tcc = c >> 1, bb = c & 1;
                    xv[j] = *(const float4*)(&xs[bb][tcc * INPUT_D + kq * 4]);
                }
                #pragma unroll
                for (int i2 = 0; i2 < 4; ++i2) {
                    const float4 wv =
                        *(const float4*)(Wih0 + (size_t)(ra + i2) * INPUT_D + kq * 4);
                    #pragma unroll
                    for (int j = 0; j < 4; ++j) {
                        acc[i2][j] = fmaf(wv.x, xv[j].x, acc[i2][j]);
                        acc[i2][j] = fmaf(wv.y, xv[j].y, acc[i2][j]);
                        acc[i2][j] = fmaf(wv.z, xv[j].z, acc[i2][j]);
                        acc[i2][j] = fmaf(wv.w, xv[j].w, acc[i2][j]);
                    }
                }
            }
            #pragma unroll
            for (int j = 0; j < 4; ++j) {
                const int c = cg * 4 + j, tcc = c >> 1, bb = c & 1;
                *(float4*)(&xg[tcc][bb][ra]) =
                    make_float4(acc[0][j], acc[1][j], acc[2][j], acc[3][j]);
            }
        }
        __syncthreads();

        // ---------- recurrent steps: 2 phases, 2 barriers per step ----------
        #pragma unroll 1
        for (int tc = 0; tc < TC; ++tc) {
            const int tg = ch * TC + tc;

            // ---- phase U: L0 update(tg) on waves 0-1, L1 update(tg-1) on 2-3
            if (t < 128) {
                float sv[4];
                #pragma unroll
                for (int g = 0; g < 4; ++g) {
                    const int rg = g * 64 + ut;
                    sv[g] = pL0[0][ub][rg] + pL0[1][ub][rg] + xg[tc][ub][rg];
                }
                const float iv = sigm(sv[0]), fv = sigm(sv[1]);
                const float gv = tanh_f(sv[2]), ov = sigm(sv[3]);
                c0 = fmaf(fv, c0, iv * gv);
                h0s[ub][ut] = ov * tanh_f(c0);
            } else if (tg > 0) {
                float sv[4];
                #pragma unroll
                for (int g = 0; g < 4; ++g) {
                    const int rg = g * 64 + ut;
                    sv[g] = pL1[0][ub][rg] + pL1[1][ub][rg]
                          + pW1[0][ub][rg] + pW1[1][ub][rg] + b1r[g];
                }
                const float iv = sigm(sv[0]), fv = sigm(sv[1]);
                const float gv = tanh_f(sv[2]), ov = sigm(sv[3]);
                c1 = fmaf(fv, c1, iv * gv);
                const float h = ov * tanh_f(c1);
                h1s[ub][ut] = h;
                float pr = fw * h;
                #pragma unroll
                for (int off = 32; off >= 1; off >>= 1) pr += __shfl_xor(pr, off, 64);
                if (ut == 0) y[(size_t)(bbase + ub) * SEQT + (tg - 1)] = pr + fb;
            }
            __syncthreads();   // h0(tg), h1(tg-1) visible

            // ---- phase M: 3 dots via LDS uniform broadcast ----
            {
                float aL0[2][2] = {{0.f, 0.f}, {0.f, 0.f}};
                float aL1[2][2] = {{0.f, 0.f}, {0.f, 0.f}};
                float aW1[2][2] = {{0.f, 0.f}, {0.f, 0.f}};
                const int kb = kh * 32;
                #pragma unroll
                for (int kq = 0; kq < 8; ++kq) {
                    float h00[4], h01[4];
                    *(float4*)h00 = *(const float4*)(&h0s[0][kb + kq * 4]);
                    *(float4*)h01 = *(const float4*)(&h0s[1][kb + kq * 4]);
                    #pragma unroll
                    for (int e = 0; e < 4; ++e) {
                        const int kk = kq * 4 + e;
                        aL0[0][0] = fmaf(w0a[kk], h00[e], aL0[0][0]);
                        aL0[0][1] = fmaf(w0a[kk], h01[e], aL0[0][1]);
                        aL0[1][0] = fmaf(w0b[kk], h00[e], aL0[1][0]);
                        aL0[1][1] = fmaf(w0b[kk], h01[e], aL0[1][1]);
                        aL1[0][0] = fmaf(wia[kk], h00[e], aL1[0][0]);
                        aL1[0][1] = fmaf(wia[kk], h01[e], aL1[0][1]);
                        aL1[1][0] = fmaf(wib[kk], h00[e], aL1[1][0]);
                        aL1[1][1] = fmaf(wib[kk], h01[e], aL1[1][1]);
                    }
                }
                #pragma unroll
                for (int kq = 0; kq < 8; ++kq) {
                    float h10[4], h11[4];
                    *(float4*)h10 = *(const float4*)(&h1s[0][kb + kq * 4]);
                    *(float4*)h11 = *(const float4*)(&h1s[1][kb + kq * 4]);
                    #pragma unroll
                    for (int e = 0; e < 4; ++e) {
                        const int kk = kq * 4 + e;
                        aW1[0][0] = fmaf(wha[kk], h10[e], aW1[0][0]);
                        aW1[0][1] = fmaf(wha[kk], h11[e], aW1[0][1]);
                        aW1[1][0] = fmaf(whb[kk], h10[e], aW1[1][0]);
                        aW1[1][1] = fmaf(whb[kk], h11[e], aW1[1][1]);
                    }
                }
                pL0[kh][0][rp]       = aL0[0][0];
                pL0[kh][1][rp]       = aL0[0][1];
                pL0[kh][0][rp + 128] = aL0[1][0];
                pL0[kh][1][rp + 128] = aL0[1][1];
                pL1[kh][0][rp]       = aL1[0][0];
                pL1[kh][1][rp]       = aL1[0][1];
                pL1[kh][0][rp + 128] = aL1[1][0];
                pL1[kh][1][rp + 128] = aL1[1][1];
                pW1[kh][0][rp]       = aW1[0][0];
                pW1[kh][1][rp]       = aW1[0][1];
                pW1[kh][0][rp + 128] = aW1[1][0];
                pW1[kh][1][rp + 128] = aW1[1][1];
            }
            __syncthreads();   // partials visible for next U
        }
    }

    // ---------- epilogue: L1 update for step 511 ----------
    if (t >= 128) {
        float sv[4];
        #pragma unroll
        for (int g = 0; g < 4; ++g) {
            const int rg = g * 64 + ut;
            sv[g] = pL1[0][ub][rg] + pL1[1][ub][rg]
                  + pW1[0][ub][rg] + pW1[1][ub][rg] + b1r[g];
        }
        const float iv = sigm(sv[0]), fv = sigm(sv[1]);
        const float gv = tanh_f(sv[2]), ov = sigm(sv[3]);
        c1 = fmaf(fv, c1, iv * gv);
        const float h = ov * tanh_f(c1);
        float pr = fw * h;
        #pragma unroll
        for (int off = 32; off >= 1; off >>= 1) pr += __shfl_xor(pr, off, 64);
        if (ut == 0) y[(size_t)(bbase + ub) * SEQT + (SEQT - 1)] = pr + fb;
    }
}

extern "C" void kernel_launch(void* const* d_in, const int* in_sizes, int n_in,
                              void* d_out, int out_size, void* d_ws, size_t ws_size,
                              hipStream_t stream) {
    const float* x    = (const float*)d_in[0];
    const float* Wih0 = (const float*)d_in[1];
    const float* Whh0 = (const float*)d_in[2];
    const float* bih0 = (const float*)d_in[3];
    const float* bhh0 = (const float*)d_in[4];
    const float* Wih1 = (const float*)d_in[5];
    const float* Whh1 = (const float*)d_in[6];
    const float* bih1 = (const float*)d_in[7];
    const float* bhh1 = (const float*)d_in[8];
    const float* fcw  = (const float*)d_in[9];
    const float* fcb  = (const float*)d_in[10];
    float* y = (float*)d_out;

    lstm2_fused<<<NB, 256, 0, stream>>>(x, Wih0, Whh0, bih0, bhh0,
                                        Wih1, Whh1, bih1, bhh1, fcw, fcb, y);
}